// Round 12
// baseline (26038.354 us; speedup 1.0000x reference)
//
#include <hip/hip_runtime.h>
#include <cstdint>
#include <cstddef>

#define TCHUNK 128
#define NCHUNK 8
#define BATCH 32
#define IDIM 128
#define HDIM 512
#define GDIM 2048
#define ODIM 10
#define NBLK 256
#define XPSTEP (GDIM * BATCH)
#define SLAB_F 16384            // floats per t-slab: 8 groups x 4 chains x 512
#define SLAB_B (SLAB_F * 4)

typedef float f4 __attribute__((ext_vector_type(4)));
typedef float f2 __attribute__((ext_vector_type(2)));

// LLC-visible store (sc0 sc1): one-way, fire-and-forget, placement-independent
__device__ __forceinline__ void llc_store(float* p, float v) {
  asm volatile("global_store_dword %0, %1, off sc0 sc1" :: "v"(p), "v"(v) : "memory");
}
__device__ __forceinline__ float dpp_xor1(float x) {
  return __int_as_float(__builtin_amdgcn_update_dpp(0, __float_as_int(x), 0xB1, 0xF, 0xF, true));
}
__device__ __forceinline__ float dpp_xor2(float x) {
  return __int_as_float(__builtin_amdgcn_update_dpp(0, __float_as_int(x), 0x4E, 0xF, 0xF, true));
}
__device__ __forceinline__ float dpp_ror4(float x) {
  return __int_as_float(__builtin_amdgcn_update_dpp(0, __float_as_int(x), 0x124, 0xF, 0xF, true));
}
__device__ __forceinline__ float dpp_ror8(float x) {
  return __int_as_float(__builtin_amdgcn_update_dpp(0, __float_as_int(x), 0x128, 0xF, 0xF, true));
}

// ---------------------------------------------------------------------------
// proj: P[tt][n][b] = sum_k X[tt*32+b][k] * W[n][k] + bias[n]
// ---------------------------------------------------------------------------
template<int K>
__launch_bounds__(256, 2)
__global__ void proj_kernel(const float* __restrict__ X,
                            const float* __restrict__ W,
                            const float* __restrict__ bias,
                            float* __restrict__ P) {
  __shared__ float Xs[8][132];
  __shared__ float Ws[8][132];
  const int tid = threadIdx.x;
  const int n0 = blockIdx.x * 128;
  const int m0 = blockIdx.y * 128;
  const int tx = tid & 15, ty = tid >> 4;
  const int lm = tid >> 1;
  const int kq = (tid & 1) * 4;
  f2 acc2[8][4];
#pragma unroll
  for (int i = 0; i < 8; ++i)
#pragma unroll
    for (int j = 0; j < 4; ++j) acc2[i][j] = (f2){0.f, 0.f};

  for (int k0 = 0; k0 < K; k0 += 8) {
    const float4 xv = *(const float4*)&X[(size_t)(m0 + lm) * K + k0 + kq];
    const float4 wv = *(const float4*)&W[(size_t)(n0 + lm) * K + k0 + kq];
    __syncthreads();
    Xs[kq + 0][lm] = xv.x; Xs[kq + 1][lm] = xv.y; Xs[kq + 2][lm] = xv.z; Xs[kq + 3][lm] = xv.w;
    Ws[kq + 0][lm] = wv.x; Ws[kq + 1][lm] = wv.y; Ws[kq + 2][lm] = wv.z; Ws[kq + 3][lm] = wv.w;
    __syncthreads();
#pragma unroll
    for (int kk = 0; kk < 8; ++kk) {
      float a[8];
      *(float4*)&a[0] = *(const float4*)&Xs[kk][ty * 8];
      *(float4*)&a[4] = *(const float4*)&Xs[kk][ty * 8 + 4];
      f2 b2[4];
#pragma unroll
      for (int jp = 0; jp < 4; ++jp) b2[jp] = *(const f2*)&Ws[kk][tx * 8 + 2 * jp];
#pragma unroll
      for (int i = 0; i < 8; ++i)
#pragma unroll
        for (int jp = 0; jp < 4; ++jp) acc2[i][jp] += b2[jp] * a[i];
    }
  }
  const int mb = m0 + ty * 8;
  const int t  = mb >> 5;
  const int b0 = mb & 31;
#pragma unroll
  for (int j = 0; j < 8; ++j) {
    const int n = n0 + tx * 8 + j;
    const float bj = bias[n];
    float* dst = &P[((size_t)t * GDIM + n) * BATCH + b0];
#pragma unroll
    for (int i = 0; i < 8; ++i)
      dst[i] = ((j & 1) ? acc2[i][j >> 1].y : acc2[i][j >> 1].x) + bj;
  }
}

// ---------------------------------------------------------------------------
// scan: barrier-free, wave-autonomous sentinel-exchange LSTM recurrence.
// 256 blocks, 1/CU (82KB LDS). Group g=bid&7 owns batches 4g..4g+3;
// rank=bid>>3 owns h-slots rank*16..+15. Wave w owns slots slot16+4w..+3 and
// is a SELF-CONTAINED engine: it polls all 32 producers, stages the full 8KB
// group-h into its PRIVATE LDS buffer, computes, reduces in-wave, updates.
// No s_barrier anywhere; within-wave DS ordering via lgkmcnt + sched_barrier.
//   lane (rg=l>>4, s16=l&15): W = 4 gate rows of slot (slot16+4w+rg),
//   k in [32*s16, +32). acc[q][c] over 4 chains. Butterfly over s16 with
//   chain specialization (xor1,xor2 DPP keep chain=s16&3; ror4,ror8 finish)
//   -> all 4 gates of (slot, chain=s16&3) land in-lane. Lanes s16<4 do the
//   gate tail and one sc0sc1 h-store.
// LDS h layout per wave: [slice m][4*kk + chain], slice stride 132 (pad) ->
// writes 2 lanes/bank (free), reads linear imm-offset, 2-way + broadcast.
// Exchange: write-once slabs hb[t][g][chain][512], sentinel 0xFFFFFFFF.
// ---------------------------------------------------------------------------
__launch_bounds__(256, 1)
__global__ void scan_kernel(const float* __restrict__ xp,    // [TCHUNK][GDIM][BATCH]
                            const float* __restrict__ Whh,   // [GDIM][HDIM]
                            float* __restrict__ hout,        // [TCHUNK][BATCH][HDIM]
                            float* __restrict__ hb,          // [TCHUNK+1][8][4][512]
                            float* __restrict__ ccur,        // [BATCH][HDIM]
                            int first) {
  __shared__ float h_all[4][2112];  // per-wave private h buffers
  __shared__ float pad[12288];      // 48KB -> 81KB total -> 1 block/CU

  const int tid = threadIdx.x, bid = blockIdx.x;
  const int g = bid & 7, rank = bid >> 3, slot16 = rank * 16;
  const int w = tid >> 6, l = tid & 63;
  const int rg = l >> 4, s16 = l & 15;
  const int slot = slot16 + 4 * w + rg;

  // ---- W: 4 gate rows of `slot`, k in [32*s16, +32), into VGPRs ----
  float wreg[4][32];
#pragma unroll
  for (int q = 0; q < 4; ++q) {
    const float* wp = Whh + (size_t)(q * HDIM + slot) * HDIM + 32 * s16;
#pragma unroll
    for (int q8 = 0; q8 < 8; ++q8) {
      const f4 v = *(const f4*)&wp[q8 * 4];
      wreg[q][q8 * 4 + 0] = v.x; wreg[q][q8 * 4 + 1] = v.y;
      wreg[q][q8 * 4 + 2] = v.z; wreg[q][q8 * 4 + 3] = v.w;
    }
  }

  // staging role: lane (cl = l>>4, m = l&15) stages chain cl, k [32m, 32m+32)
  const int cl = rg, m = s16;
  float* hw = &h_all[w][132 * m + cl];          // writes: hw[16*i + 4*j]
  const float* hr = &h_all[w][132 * s16];       // reads: hr[4*kk + c]
  const int srcoff = cl * 512 + 32 * m;

  // tail role (lanes s16 < 4): cell (slot, chain c0 = s16&3)
  const int c0 = s16 & 3;
  const size_t xqo = (size_t)slot * BATCH + g * 4 + c0;   // + q*HDIM*BATCH per gate
  const size_t cco = (size_t)(g * 4 + c0) * HDIM + slot;

  float c_st = 0.f;
  if (!first && s16 < 4) c_st = ccur[cco];

  const int p1 = s16 & 1, p2 = (s16 >> 1) & 1;

#pragma unroll 1
  for (int tt = 0; tt < TCHUNK; ++tt) {
    __builtin_amdgcn_sched_barrier(0);
    // ---- poll + load h(tt): data is the flag (8 x dwordx4 per lane) ----
    const float* src = hb + (size_t)tt * SLAB_F + g * 2048 + srcoff;
    f4 v0, v1, v2, v3, v4, v5, v6, v7;
    int guard = 0;
    while (true) {
      asm volatile(
          "global_load_dwordx4 %0, %8, off sc0 sc1\n\t"
          "global_load_dwordx4 %1, %8, off offset:16 sc0 sc1\n\t"
          "global_load_dwordx4 %2, %8, off offset:32 sc0 sc1\n\t"
          "global_load_dwordx4 %3, %8, off offset:48 sc0 sc1\n\t"
          "global_load_dwordx4 %4, %8, off offset:64 sc0 sc1\n\t"
          "global_load_dwordx4 %5, %8, off offset:80 sc0 sc1\n\t"
          "global_load_dwordx4 %6, %8, off offset:96 sc0 sc1\n\t"
          "global_load_dwordx4 %7, %8, off offset:112 sc0 sc1\n\t"
          "s_waitcnt vmcnt(0)"
          : "=&v"(v0), "=&v"(v1), "=&v"(v2), "=&v"(v3),
            "=&v"(v4), "=&v"(v5), "=&v"(v6), "=&v"(v7)
          : "v"(src) : "memory");
      unsigned acc = 0xFFFFFFFFu;
#define CHK(V) acc &= (__float_as_uint(V.x) ^ 0xFFFFFFFFu) | (__float_as_uint(V.y) ^ 0xFFFFFFFFu), \
               acc &= (__float_as_uint(V.z) ^ 0xFFFFFFFFu) | (__float_as_uint(V.w) ^ 0xFFFFFFFFu)
      // simpler & robust: direct comparisons
#undef CHK
      const bool ok =
          __float_as_uint(v0.x) != 0xFFFFFFFFu && __float_as_uint(v0.y) != 0xFFFFFFFFu &&
          __float_as_uint(v0.z) != 0xFFFFFFFFu && __float_as_uint(v0.w) != 0xFFFFFFFFu &&
          __float_as_uint(v1.x) != 0xFFFFFFFFu && __float_as_uint(v1.y) != 0xFFFFFFFFu &&
          __float_as_uint(v1.z) != 0xFFFFFFFFu && __float_as_uint(v1.w) != 0xFFFFFFFFu &&
          __float_as_uint(v2.x) != 0xFFFFFFFFu && __float_as_uint(v2.y) != 0xFFFFFFFFu &&
          __float_as_uint(v2.z) != 0xFFFFFFFFu && __float_as_uint(v2.w) != 0xFFFFFFFFu &&
          __float_as_uint(v3.x) != 0xFFFFFFFFu && __float_as_uint(v3.y) != 0xFFFFFFFFu &&
          __float_as_uint(v3.z) != 0xFFFFFFFFu && __float_as_uint(v3.w) != 0xFFFFFFFFu &&
          __float_as_uint(v4.x) != 0xFFFFFFFFu && __float_as_uint(v4.y) != 0xFFFFFFFFu &&
          __float_as_uint(v4.z) != 0xFFFFFFFFu && __float_as_uint(v4.w) != 0xFFFFFFFFu &&
          __float_as_uint(v5.x) != 0xFFFFFFFFu && __float_as_uint(v5.y) != 0xFFFFFFFFu &&
          __float_as_uint(v5.z) != 0xFFFFFFFFu && __float_as_uint(v5.w) != 0xFFFFFFFFu &&
          __float_as_uint(v6.x) != 0xFFFFFFFFu && __float_as_uint(v6.y) != 0xFFFFFFFFu &&
          __float_as_uint(v6.z) != 0xFFFFFFFFu && __float_as_uint(v6.w) != 0xFFFFFFFFu &&
          __float_as_uint(v7.x) != 0xFFFFFFFFu && __float_as_uint(v7.y) != 0xFFFFFFFFu &&
          __float_as_uint(v7.z) != 0xFFFFFFFFu && __float_as_uint(v7.w) != 0xFFFFFFFFu;
      if (__all(ok) || ++guard > 200000) break;
      __builtin_amdgcn_s_sleep(1);
    }
    // ---- stage into this wave's private buffer (b32, 2 lanes/bank) ----
    __builtin_amdgcn_sched_barrier(0);
#define PUT(I, V) hw[16*(I) + 0] = V.x; hw[16*(I) + 4] = V.y; \
                  hw[16*(I) + 8] = V.z; hw[16*(I) + 12] = V.w;
    PUT(0, v0) PUT(1, v1) PUT(2, v2) PUT(3, v3)
    PUT(4, v4) PUT(5, v5) PUT(6, v6) PUT(7, v7)
#undef PUT
    asm volatile("s_waitcnt lgkmcnt(0)" ::: "memory");
    __builtin_amdgcn_sched_barrier(0);

    // ---- dot: 4 gates x 4 chains over this lane's 32-k slice ----
    f2 a01[4], a23[4];
#pragma unroll
    for (int q = 0; q < 4; ++q) { a01[q] = (f2){0.f, 0.f}; a23[q] = (f2){0.f, 0.f}; }
#pragma unroll
    for (int kk = 0; kk < 32; ++kk) {
      const f4 hv = *(const f4*)&hr[4 * kk];
      const f2 h01 = {hv.x, hv.y}, h23 = {hv.z, hv.w};
#pragma unroll
      for (int q = 0; q < 4; ++q) {
        a01[q] += h01 * wreg[q][kk];
        a23[q] += h23 * wreg[q][kk];
      }
    }
    __builtin_amdgcn_sched_barrier(0);

    // ---- in-wave reduce over s16 with chain specialization ----
    // stage 1 (xor1): keep chain low-bit == s16&1
    float k0v[4], k1v[4];                 // kept: chains {p1, 2+p1}
#pragma unroll
    for (int q = 0; q < 4; ++q) {
      const float keep0 = p1 ? a01[q].y : a01[q].x;   // chain 0-pair kept
      const float send0 = p1 ? a01[q].x : a01[q].y;
      const float keep1 = p1 ? a23[q].y : a23[q].x;   // chain 2-pair kept
      const float send1 = p1 ? a23[q].x : a23[q].y;
      k0v[q] = keep0 + dpp_xor1(send0);
      k1v[q] = keep1 + dpp_xor1(send1);
    }
    // stage 2 (xor2): keep chain high-bit == (s16>>1)&1
    float bqv[4];
#pragma unroll
    for (int q = 0; q < 4; ++q) {
      const float keep = p2 ? k1v[q] : k0v[q];
      const float send = p2 ? k0v[q] : k1v[q];
      bqv[q] = keep + dpp_xor2(send);
    }
    // stages 3,4 (ror4, ror8): sum the 4 slice-quads
#pragma unroll
    for (int q = 0; q < 4; ++q) {
      bqv[q] += dpp_ror4(bqv[q]);
      bqv[q] += dpp_ror8(bqv[q]);
    }

    // ---- tail: lanes s16 < 4 own cell (slot, chain c0) ----
    if (s16 < 4) {
      const float* xb = xp + (size_t)tt * XPSTEP + xqo;
      const float ig = 1.f / (1.f + __expf(-(bqv[0] + xb[0])));
      const float fg = 1.f / (1.f + __expf(-(bqv[1] + xb[(size_t)HDIM * BATCH])));
      const float gg = tanhf(bqv[2] + xb[(size_t)2 * HDIM * BATCH]);
      const float og = 1.f / (1.f + __expf(-(bqv[3] + xb[(size_t)3 * HDIM * BATCH])));
      c_st = fg * c_st + ig * gg;
      const float hval = og * tanhf(c_st);
      llc_store(hb + (size_t)(tt + 1) * SLAB_F + g * 2048 + c0 * 512 + slot, hval);
      hout[(size_t)tt * (BATCH * HDIM) + (size_t)(g * 4 + c0) * HDIM + slot] = hval;
    }
  }
  if (s16 < 4) ccur[cco] = c_st;
  ((volatile float*)pad)[tid] = c_st;           // keep LDS pad allocated
}

// ---------------------------------------------------------------------------
// head: logits = h2 @ W3^T + b3 ; softmax over 10. One wave per row.
// ---------------------------------------------------------------------------
__launch_bounds__(256, 2)
__global__ void head_kernel(const float* __restrict__ h2,
                            const float* __restrict__ W3,
                            const float* __restrict__ b3,
                            float* __restrict__ outp) {
  const int tid = threadIdx.x;
  const int lane = tid & 63;
  const int wv = tid >> 6;
  const int row = blockIdx.x * 4 + wv;
  const float* hrow = &h2[(size_t)row * HDIM];
  float hreg[8];
  *(float4*)&hreg[0] = *(const float4*)&hrow[lane * 8];
  *(float4*)&hreg[4] = *(const float4*)&hrow[lane * 8 + 4];
  float logit[ODIM];
#pragma unroll
  for (int o = 0; o < ODIM; ++o) {
    const float* wrow = &W3[o * HDIM + lane * 8];
    float w[8];
    *(float4*)&w[0] = *(const float4*)&wrow[0];
    *(float4*)&w[4] = *(const float4*)&wrow[4];
    float pp = 0.f;
#pragma unroll
    for (int j = 0; j < 8; ++j) pp += hreg[j] * w[j];
#pragma unroll
    for (int off = 32; off > 0; off >>= 1) pp += __shfl_xor(pp, off);
    logit[o] = pp + b3[o];
  }
  float mx = logit[0];
#pragma unroll
  for (int o = 1; o < ODIM; ++o) mx = fmaxf(mx, logit[o]);
  float ssum = 0.f;
#pragma unroll
  for (int o = 0; o < ODIM; ++o) { logit[o] = __expf(logit[o] - mx); ssum += logit[o]; }
  const float inv = 1.f / ssum;
  if (lane == 0) {
    float* dst = &outp[(size_t)row * ODIM];
#pragma unroll
    for (int o = 0; o < ODIM; ++o) dst[o] = logit[o] * inv;
  }
}

// ---------------------------------------------------------------------------
extern "C" void kernel_launch(void* const* d_in, const int* in_sizes, int n_in,
                              void* d_out, int out_size, void* d_ws, size_t ws_size,
                              hipStream_t stream) {
  const float* data  = (const float*)d_in[0];
  const float* W_ih1 = (const float*)d_in[1];
  const float* W_hh1 = (const float*)d_in[2];
  const float* b1    = (const float*)d_in[3];
  const float* W_ih2 = (const float*)d_in[4];
  const float* W_hh2 = (const float*)d_in[5];
  const float* b2    = (const float*)d_in[6];
  const float* W3    = (const float*)d_in[7];
  const float* b3    = (const float*)d_in[8];
  float* outp = (float*)d_out;

  char* ws = (char*)d_ws;
  size_t off = 0;
  float* xp    = (float*)(ws + off); off += (size_t)TCHUNK * GDIM * BATCH * 4;     // 32MB
  float* h1c   = (float*)(ws + off); off += (size_t)TCHUNK * BATCH * HDIM * 4;     // 8MB
  float* h2c   = (float*)(ws + off); off += (size_t)TCHUNK * BATCH * HDIM * 4;     // 8MB
  float* hb1   = (float*)(ws + off); off += (size_t)(TCHUNK + 1) * SLAB_B;         // 8.45MB
  float* hb2   = (float*)(ws + off); off += (size_t)(TCHUNK + 1) * SLAB_B;
  float* ccur1 = (float*)(ws + off); off += BATCH * HDIM * 4;
  float* ccur2 = (float*)(ws + off); off += BATCH * HDIM * 4;
  if (off > ws_size) return;   // ws too small: bail visibly

  // slab 0 = h(0) = zeros; slabs 1..TCHUNK = sentinel 0xFFFFFFFF
  hipMemsetAsync(hb1, 0x00, SLAB_B, stream);
  hipMemsetAsync((char*)hb1 + SLAB_B, 0xFF, (size_t)TCHUNK * SLAB_B, stream);
  hipMemsetAsync(hb2, 0x00, SLAB_B, stream);
  hipMemsetAsync((char*)hb2 + SLAB_B, 0xFF, (size_t)TCHUNK * SLAB_B, stream);

  const dim3 pgrid(GDIM / 128, (TCHUNK * BATCH) / 128);
  for (int c = 0; c < NCHUNK; ++c) {
    const float* xin = data + (size_t)c * TCHUNK * BATCH * IDIM;
    proj_kernel<IDIM><<<pgrid, 256, 0, stream>>>(xin, W_ih1, b1, xp);
    scan_kernel<<<NBLK, 256, 0, stream>>>(xp, W_hh1, h1c, hb1, ccur1, c == 0);
    if (c < NCHUNK - 1) {   // recycle slabs: h(end) -> slab0, re-sentinel
      hipMemcpyAsync(hb1, (char*)hb1 + (size_t)TCHUNK * SLAB_B, SLAB_B,
                     hipMemcpyDeviceToDevice, stream);
      hipMemsetAsync((char*)hb1 + SLAB_B, 0xFF, (size_t)TCHUNK * SLAB_B, stream);
    }
    proj_kernel<HDIM><<<pgrid, 256, 0, stream>>>(h1c, W_ih2, b2, xp);
    scan_kernel<<<NBLK, 256, 0, stream>>>(xp, W_hh2, h2c, hb2, ccur2, c == 0);
    if (c < NCHUNK - 1) {
      hipMemcpyAsync(hb2, (char*)hb2 + (size_t)TCHUNK * SLAB_B, SLAB_B,
                     hipMemcpyDeviceToDevice, stream);
      hipMemsetAsync((char*)hb2 + SLAB_B, 0xFF, (size_t)TCHUNK * SLAB_B, stream);
    }
    head_kernel<<<(TCHUNK * BATCH) / 4, 256, 0, stream>>>(
        h2c, W3, b3, outp + (size_t)c * TCHUNK * BATCH * ODIM);
  }
}

// Round 13
// 11377.872 us; speedup vs baseline: 2.2885x; 2.2885x over previous
//
#include <hip/hip_runtime.h>
#include <cstdint>
#include <cstddef>

#define TCHUNK 64
#define NCHUNK 16
#define BATCH 32
#define IDIM 128
#define HDIM 512
#define GDIM 2048
#define ODIM 10
#define NBLK 256
#define XPSTEP (GDIM * BATCH)
#define SLAB_F 16384            // floats per t-slab: 8 groups x 4 chains x 512
#define SLAB_B (SLAB_F * 4)

typedef float f4 __attribute__((ext_vector_type(4)));
typedef float f2 __attribute__((ext_vector_type(2)));

__device__ __forceinline__ void llc_store(float* p, float v) {
  asm volatile("global_store_dword %0, %1, off sc0 sc1" :: "v"(p), "v"(v) : "memory");
}
__device__ __forceinline__ float quad_sum(float x) {
  int t = __builtin_amdgcn_update_dpp(0, __float_as_int(x), 0xB1, 0xF, 0xF, true);
  x += __int_as_float(t);
  t = __builtin_amdgcn_update_dpp(0, __float_as_int(x), 0x4E, 0xF, 0xF, true);
  x += __int_as_float(t);
  return x;
}

#define BARRIER() do {                                                      \
    asm volatile("s_waitcnt lgkmcnt(0)" ::: "memory");                      \
    __builtin_amdgcn_sched_barrier(0);                                      \
    __builtin_amdgcn_s_barrier();                                           \
    __builtin_amdgcn_sched_barrier(0);                                      \
  } while (0)

// ---------------------------------------------------------------------------
// proj: P[tt][n][b] = sum_k X[tt*32+b][k] * W[n][k] + bias[n]
// ---------------------------------------------------------------------------
template<int K>
__launch_bounds__(256, 2)
__global__ void proj_kernel(const float* __restrict__ X,
                            const float* __restrict__ W,
                            const float* __restrict__ bias,
                            float* __restrict__ P) {
  __shared__ float Xs[8][132];
  __shared__ float Ws[8][132];
  const int tid = threadIdx.x;
  const int n0 = blockIdx.x * 128;
  const int m0 = blockIdx.y * 128;
  const int tx = tid & 15, ty = tid >> 4;
  const int lm = tid >> 1;
  const int kq = (tid & 1) * 4;
  f2 acc2[8][4];
#pragma unroll
  for (int i = 0; i < 8; ++i)
#pragma unroll
    for (int j = 0; j < 4; ++j) acc2[i][j] = (f2){0.f, 0.f};

  for (int k0 = 0; k0 < K; k0 += 8) {
    const float4 xv = *(const float4*)&X[(size_t)(m0 + lm) * K + k0 + kq];
    const float4 wv = *(const float4*)&W[(size_t)(n0 + lm) * K + k0 + kq];
    __syncthreads();
    Xs[kq + 0][lm] = xv.x; Xs[kq + 1][lm] = xv.y; Xs[kq + 2][lm] = xv.z; Xs[kq + 3][lm] = xv.w;
    Ws[kq + 0][lm] = wv.x; Ws[kq + 1][lm] = wv.y; Ws[kq + 2][lm] = wv.z; Ws[kq + 3][lm] = wv.w;
    __syncthreads();
#pragma unroll
    for (int kk = 0; kk < 8; ++kk) {
      float a[8];
      *(float4*)&a[0] = *(const float4*)&Xs[kk][ty * 8];
      *(float4*)&a[4] = *(const float4*)&Xs[kk][ty * 8 + 4];
      f2 b2[4];
#pragma unroll
      for (int jp = 0; jp < 4; ++jp) b2[jp] = *(const f2*)&Ws[kk][tx * 8 + 2 * jp];
#pragma unroll
      for (int i = 0; i < 8; ++i)
#pragma unroll
        for (int jp = 0; jp < 4; ++jp) acc2[i][jp] += b2[jp] * a[i];
    }
  }
  const int mb = m0 + ty * 8;
  const int t  = mb >> 5;
  const int b0 = mb & 31;
#pragma unroll
  for (int j = 0; j < 8; ++j) {
    const int n = n0 + tx * 8 + j;
    const float bj = bias[n];
    float* dst = &P[((size_t)t * GDIM + n) * BATCH + b0];
#pragma unroll
    for (int i = 0; i < 8; ++i)
      dst[i] = ((j & 1) ? acc2[i][j >> 1].y : acc2[i][j >> 1].x) + bj;
  }
}

// ---------------------------------------------------------------------------
// scan_split: space-split dual-layer R10 engine.
// Blocks 0..127 -> layer 1 (this slot's chunk), 128..255 -> layer 2. Each
// half: 8 groups x 16 ranks; rank owns 32 h-slots (128 W rows in VGPRs as
// two 64-row banks A=gates{i,f}, B=gates{g,o}; R10 column-permute e^cx).
// Engine per step is R10 verbatim: sentinel poll + octet-swizzled staging
// into padded h_s (conflict-free linear b128 reads), dot (run per bank),
// quad-DPP + cross-wave red reduce (per bank), gate activation (512 cells,
// 2/thread), tail update on waves 0,1 (128 cells), one sc0sc1 store.
// No coupling between the halves: separate W, polls, sentinels, slabs.
// ---------------------------------------------------------------------------
__launch_bounds__(256, 1)
__global__ void scan_split(const float* __restrict__ xp1, const float* __restrict__ Whh1,
                           float* __restrict__ hout1, float* __restrict__ hb1,
                           float* __restrict__ ccur1, int first1, int act1,
                           const float* __restrict__ xp2, const float* __restrict__ Whh2,
                           float* __restrict__ hout2, float* __restrict__ hb2,
                           float* __restrict__ ccur2, int first2, int act2) {
  __shared__ float h_s[2112];       // 16 slices x 132 floats (4-float pad)
  __shared__ float red[2048];       // bank A: [0,1024), bank B: [1024,2048)
  __shared__ float gate_s[512];     // [lrow 0..127][chain]
  __shared__ float pad[15872];      // -> 82176B total -> 1 block/CU

  const int bid = blockIdx.x;
  const int lay = bid >> 7;
  if (!(lay ? act2 : act1)) return;
  const float* xp  = lay ? xp2  : xp1;
  const float* Whh = lay ? Whh2 : Whh1;
  float* hout = lay ? hout2 : hout1;
  float* hb   = lay ? hb2   : hb1;
  float* ccur = lay ? ccur2 : ccur1;
  const int first = lay ? first2 : first1;

  const int tid = threadIdx.x;
  const int bidl = bid & 127;
  const int g = bidl & 7, rank = bidl >> 3, slot32 = rank * 32;
  const int w = tid >> 6, l = tid & 63;
  const int s4 = l & 3, rq = l >> 2;
  const int sg = 4 * w + s4;
  const int cx = sg & 7;
  const int kb = 32 * sg;

  // ---- W banks into VGPRs, column-permuted (R10 scheme, x2 banks) ----
  float wA[4][32], wB[4][32];
#pragma unroll
  for (int r = 0; r < 4; ++r) {
    const int rl = 4 * rq + r;                   // row within bank, 0..63
    const int s = rl & 31;
    const float* wpA = Whh + (size_t)((rl >> 5) * HDIM + slot32 + s) * HDIM + kb;
    const float* wpB = Whh + (size_t)((2 + (rl >> 5)) * HDIM + slot32 + s) * HDIM + kb;
#pragma unroll
    for (int e = 0; e < 32; ++e) { wA[r][e] = wpA[e ^ cx]; wB[r][e] = wpB[e ^ cx]; }
  }

  // staging role — verbatim R10
  const int cl = l >> 4, m = l & 15;
  const int sgS = 4 * w + (m >> 2);
  const int sig = sgS & 7;
  int dsaddr[8];
#pragma unroll
  for (int i = 0; i < 8; ++i)
    dsaddr[i] = 132 * sgS + 4 * (8 * (m & 3) + (i ^ sig)) + cl;
  const int srcoff = cl * 512 + 128 * w + 8 * m;

  // gate-cell role: cell A = (lrowA = tid>>2, chain tid&3), cell B = lrowA+64
  const int rowA = tid >> 2, chn = tid & 3;
  const size_t xqoA = (size_t)((rowA >> 5) * HDIM + slot32 + (rowA & 31)) * BATCH
                      + g * 4 + chn;
  const size_t xqoB = xqoA + (size_t)2 * HDIM * BATCH;

  // update role (waves 0,1): cell (slot32 + uj, chain ub)
  const int uj = ((w << 6) + l) >> 2;            // 0..31 (valid for w<2)
  const int ub = l & 3;
  const size_t cco = (size_t)(g * 4 + ub) * HDIM + slot32 + uj;

  float c_st = 0.f;
  if (!first && w < 2) c_st = ccur[cco];

  const float* hptr = &h_s[132 * sg];

#pragma unroll 1
  for (int tt = 0; tt < TCHUNK; ++tt) {
    // ---- poll + stage h(tt): data is the flag (R10 verbatim) ----
    const float* src = hb + (size_t)tt * SLAB_F + g * 2048 + srcoff;
    f4 va, vb;
    int guard = 0;
    while (true) {
      asm volatile("global_load_dwordx4 %0, %2, off sc0 sc1\n\t"
                   "global_load_dwordx4 %1, %3, off sc0 sc1\n\t"
                   "s_waitcnt vmcnt(0)"
                   : "=&v"(va), "=&v"(vb) : "v"(src), "v"(src + 4) : "memory");
      const bool ok =
          __float_as_uint(va.x) != 0xFFFFFFFFu && __float_as_uint(va.y) != 0xFFFFFFFFu &&
          __float_as_uint(va.z) != 0xFFFFFFFFu && __float_as_uint(va.w) != 0xFFFFFFFFu &&
          __float_as_uint(vb.x) != 0xFFFFFFFFu && __float_as_uint(vb.y) != 0xFFFFFFFFu &&
          __float_as_uint(vb.z) != 0xFFFFFFFFu && __float_as_uint(vb.w) != 0xFFFFFFFFu;
      if (__all(ok) || ++guard > 200000) break;
      __builtin_amdgcn_s_sleep(1);
    }
    h_s[dsaddr[0]] = va.x; h_s[dsaddr[1]] = va.y;
    h_s[dsaddr[2]] = va.z; h_s[dsaddr[3]] = va.w;
    h_s[dsaddr[4]] = vb.x; h_s[dsaddr[5]] = vb.y;
    h_s[dsaddr[6]] = vb.z; h_s[dsaddr[7]] = vb.w;
    const float xpvA = xp[(size_t)tt * XPSTEP + xqoA];
    const float xpvB = xp[(size_t)tt * XPSTEP + xqoB];
    BARRIER();                                  // h_s(tt) ready

    // ---- dot + reduce, per bank (R10 scheme) ----
#define DOT_BANK(WREG, ROFF)                                                \
    {                                                                       \
      f2 a01[4], a23[4];                                                    \
      _Pragma("unroll")                                                     \
      for (int r = 0; r < 4; ++r) { a01[r] = (f2){0.f,0.f}; a23[r] = (f2){0.f,0.f}; } \
      _Pragma("unroll")                                                     \
      for (int kk = 0; kk < 32; ++kk) {                                     \
        const f4 hv = *(const f4*)&hptr[4 * kk];                            \
        const f2 h01 = {hv.x, hv.y}, h23 = {hv.z, hv.w};                    \
        _Pragma("unroll")                                                   \
        for (int r = 0; r < 4; ++r) {                                       \
          a01[r] += h01 * WREG[r][kk];                                      \
          a23[r] += h23 * WREG[r][kk];                                      \
        }                                                                   \
      }                                                                     \
      _Pragma("unroll")                                                     \
      for (int r = 0; r < 4; ++r) {                                         \
        a01[r].x = quad_sum(a01[r].x); a01[r].y = quad_sum(a01[r].y);       \
        a23[r].x = quad_sum(a23[r].x); a23[r].y = quad_sum(a23[r].y);       \
      }                                                                     \
      f2 r01, r23;                                                          \
      { const f2 v0 = (s4 & 1) ? a01[1] : a01[0];                           \
        const f2 v1 = (s4 & 1) ? a01[3] : a01[2];                           \
        r01 = (s4 & 2) ? v1 : v0;                                           \
        const f2 u0 = (s4 & 1) ? a23[1] : a23[0];                           \
        const f2 u1 = (s4 & 1) ? a23[3] : a23[2];                           \
        r23 = (s4 & 2) ? u1 : u0; }                                         \
      *(f4*)&red[(ROFF) + (w << 8) + 4 * l] = (f4){r01.x, r01.y, r23.x, r23.y}; \
    }
    DOT_BANK(wA, 0)
    DOT_BANK(wB, 1024)
#undef DOT_BANK
    BARRIER();                                  // red(tt) ready

    // ---- final reduce + activation: 2 cells/thread ----
    {
      const float preA = red[tid] + red[256 + tid] + red[512 + tid] + red[768 + tid] + xpvA;
      gate_s[tid] = 1.f / (1.f + __expf(-preA));            // gates i,f
      const float preB = red[1024 + tid] + red[1280 + tid] + red[1536 + tid]
                       + red[1792 + tid] + xpvB;
      gate_s[256 + tid] = (tid < 128) ? tanhf(preB)          // gate g
                                      : 1.f / (1.f + __expf(-preB));  // gate o
    }
    BARRIER();                                  // gates ready

    // ---- tail: waves 0,1 update 128 cells + one-way store ----
    if (w < 2) {
      const float ig = gate_s[uj * 4 + ub];
      const float fg = gate_s[128 + uj * 4 + ub];
      const float gg = gate_s[256 + uj * 4 + ub];
      const float og = gate_s[384 + uj * 4 + ub];
      c_st = fg * c_st + ig * gg;
      const float hval = og * tanhf(c_st);
      llc_store(hb + (size_t)(tt + 1) * SLAB_F + g * 2048 + ub * 512 + slot32 + uj, hval);
      hout[(size_t)tt * (BATCH * HDIM) + cco] = hval;
    }
  }
  if (w < 2) ccur[cco] = c_st;
  ((volatile float*)pad)[tid] = c_st;           // keep LDS pad allocated
}

// ---------------------------------------------------------------------------
// head: logits = h2 @ W3^T + b3 ; softmax over 10. One wave per row.
// ---------------------------------------------------------------------------
__launch_bounds__(256, 2)
__global__ void head_kernel(const float* __restrict__ h2,
                            const float* __restrict__ W3,
                            const float* __restrict__ b3,
                            float* __restrict__ outp) {
  const int tid = threadIdx.x;
  const int lane = tid & 63;
  const int wv = tid >> 6;
  const int row = blockIdx.x * 4 + wv;
  const float* hrow = &h2[(size_t)row * HDIM];
  float hreg[8];
  *(float4*)&hreg[0] = *(const float4*)&hrow[lane * 8];
  *(float4*)&hreg[4] = *(const float4*)&hrow[lane * 8 + 4];
  float logit[ODIM];
#pragma unroll
  for (int o = 0; o < ODIM; ++o) {
    const float* wrow = &W3[o * HDIM + lane * 8];
    float w[8];
    *(float4*)&w[0] = *(const float4*)&wrow[0];
    *(float4*)&w[4] = *(const float4*)&wrow[4];
    float pp = 0.f;
#pragma unroll
    for (int j = 0; j < 8; ++j) pp += hreg[j] * w[j];
#pragma unroll
    for (int off = 32; off > 0; off >>= 1) pp += __shfl_xor(pp, off);
    logit[o] = pp + b3[o];
  }
  float mx = logit[0];
#pragma unroll
  for (int o = 1; o < ODIM; ++o) mx = fmaxf(mx, logit[o]);
  float ssum = 0.f;
#pragma unroll
  for (int o = 0; o < ODIM; ++o) { logit[o] = __expf(logit[o] - mx); ssum += logit[o]; }
  const float inv = 1.f / ssum;
  if (lane == 0) {
    float* dst = &outp[(size_t)row * ODIM];
#pragma unroll
    for (int o = 0; o < ODIM; ++o) dst[o] = logit[o] * inv;
  }
}

// ---------------------------------------------------------------------------
extern "C" void kernel_launch(void* const* d_in, const int* in_sizes, int n_in,
                              void* d_out, int out_size, void* d_ws, size_t ws_size,
                              hipStream_t stream) {
  const float* data  = (const float*)d_in[0];
  const float* W_ih1 = (const float*)d_in[1];
  const float* W_hh1 = (const float*)d_in[2];
  const float* b1    = (const float*)d_in[3];
  const float* W_ih2 = (const float*)d_in[4];
  const float* W_hh2 = (const float*)d_in[5];
  const float* b2    = (const float*)d_in[6];
  const float* W3    = (const float*)d_in[7];
  const float* b3    = (const float*)d_in[8];
  float* outp = (float*)d_out;

  char* ws = (char*)d_ws;
  size_t off = 0;
  float* xp1   = (float*)(ws + off); off += (size_t)TCHUNK * GDIM * BATCH * 4;     // 16MB
  float* xp2   = (float*)(ws + off); off += (size_t)TCHUNK * GDIM * BATCH * 4;     // 16MB
  float* h1c   = (float*)(ws + off); off += (size_t)TCHUNK * BATCH * HDIM * 4;     // 4MB
  float* h2c   = (float*)(ws + off); off += (size_t)TCHUNK * BATCH * HDIM * 4;     // 4MB
  float* hb1   = (float*)(ws + off); off += (size_t)(TCHUNK + 1) * SLAB_B;         // 4.16MB
  float* hb2   = (float*)(ws + off); off += (size_t)(TCHUNK + 1) * SLAB_B;
  float* ccur1 = (float*)(ws + off); off += BATCH * HDIM * 4;
  float* ccur2 = (float*)(ws + off); off += BATCH * HDIM * 4;
  if (off > ws_size) return;   // ws too small: bail visibly

  // slab 0 = h(0) = zeros; slabs 1..TCHUNK = sentinel 0xFFFFFFFF
  hipMemsetAsync(hb1, 0x00, SLAB_B, stream);
  hipMemsetAsync((char*)hb1 + SLAB_B, 0xFF, (size_t)TCHUNK * SLAB_B, stream);
  hipMemsetAsync(hb2, 0x00, SLAB_B, stream);
  hipMemsetAsync((char*)hb2 + SLAB_B, 0xFF, (size_t)TCHUNK * SLAB_B, stream);

  const dim3 pgrid(GDIM / 128, (TCHUNK * BATCH) / 128);

#define RECYCLE(HB) do {                                                    \
    hipMemcpyAsync(HB, (char*)HB + (size_t)TCHUNK * SLAB_B, SLAB_B,         \
                   hipMemcpyDeviceToDevice, stream);                        \
    hipMemsetAsync((char*)HB + SLAB_B, 0xFF, (size_t)TCHUNK * SLAB_B, stream); \
  } while (0)

  proj_kernel<IDIM><<<pgrid, 256, 0, stream>>>(data, W_ih1, b1, xp1);      // chunk 0

  for (int s = 0; s <= NCHUNK; ++s) {
    const int act1 = (s < NCHUNK);       // layer 1 processes chunk s
    const int act2 = (s >= 1);           // layer 2 processes chunk s-1
    scan_split<<<NBLK, 256, 0, stream>>>(
        xp1, W_hh1, h1c, hb1, ccur1, s == 0, act1,
        xp2, W_hh2, h2c, hb2, ccur2, s == 1, act2);
    if (act1) {
      RECYCLE(hb1);
      proj_kernel<HDIM><<<pgrid, 256, 0, stream>>>(h1c, W_ih2, b2, xp2);   // chunk s
      if (s + 1 < NCHUNK)
        proj_kernel<IDIM><<<pgrid, 256, 0, stream>>>(
            data + (size_t)(s + 1) * TCHUNK * BATCH * IDIM, W_ih1, b1, xp1);
    }
    if (act2) {
      if (s < NCHUNK) RECYCLE(hb2);
      head_kernel<<<(TCHUNK * BATCH) / 4, 256, 0, stream>>>(
          h2c, W3, b3, outp + (size_t)(s - 1) * TCHUNK * BATCH * ODIM);
    }
  }
#undef RECYCLE
}